// Round 1
// baseline (97.699 us; speedup 1.0000x reference)
//
#include <hip/hip_runtime.h>
#include <cstdint>

#define NTOK 16384
#define PPITCH 264

__device__ __forceinline__ float readlane_f(float v, int lane) {
  return __int_as_float(__builtin_amdgcn_readlane(__float_as_int(v), lane));
}

__device__ __forceinline__ float wave_sum64(float v) {
  #pragma unroll
  for (int s = 1; s < 64; s <<= 1) v += __shfl_xor(v, s, 64);
  return v;
}

// ---------------------------------------------------------------------------
// K1: projections. One wave per token; lane = output feature (0..63).
// Weights q,k,v,o staged in LDS as bf16 pairs packed in dwords:
//   wlds[m][j][dp ^ ((j&7)<<2)] = pack(w[2dp][j], w[2dp+1][j])
// (XOR swizzle breaks the all-lanes-same-bank pattern of the [64][64] layout)
// x is wave-uniform: 2 coalesced loads per lane, broadcast via v_readlane.
// ---------------------------------------------------------------------------
__global__ void __launch_bounds__(256, 2)
proj_kernel(const float* __restrict__ x,
            const float* __restrict__ w_q, const float* __restrict__ b_q,
            const float* __restrict__ w_k, const float* __restrict__ b_k,
            const float* __restrict__ w_v, const float* __restrict__ b_v,
            const float* __restrict__ w_i, const float* __restrict__ b_i,
            const float* __restrict__ w_f, const float* __restrict__ b_f,
            const float* __restrict__ w_o, const float* __restrict__ b_o,
            float* __restrict__ P)
{
  __shared__ uint32_t wlds[4][64][64];   // 64 KB exactly
  const int tid = threadIdx.x;
  {
    const float* Ws[4] = {w_q, w_k, w_v, w_o};
    #pragma unroll
    for (int m = 0; m < 4; ++m) {
      const float* W = Ws[m];
      #pragma unroll
      for (int it = 0; it < 16; ++it) {
        int idx = it * 256 + tid;      // 0..4095
        int dp  = idx >> 6;            // d-pair index 0..63
        int j   = idx & 63;            // column
        uint32_t ua = __float_as_uint(W[(2 * dp)     * 64 + j]);
        uint32_t ub = __float_as_uint(W[(2 * dp + 1) * 64 + j]);
        // round-to-nearest-even bf16
        ua = (ua + 0x7FFFu + ((ua >> 16) & 1u)) >> 16;
        ub = (ub + 0x7FFFu + ((ub >> 16) & 1u)) >> 16;
        wlds[m][j][dp ^ ((j & 7) << 2)] = (ua & 0xFFFFu) | (ub << 16);
      }
    }
  }
  __syncthreads();

  const int lane = tid & 63;
  const int wid  = tid >> 6;
  const float wi0 = w_i[lane], wi1 = w_i[64 + lane];
  const float wf0 = w_f[lane], wf1 = w_f[64 + lane];
  const float bq = b_q[lane], bk = b_k[lane], bv = b_v[lane], bo = b_o[lane];
  const float sbi = b_i[0], sbf = b_f[0];

  const int gw = (blockIdx.x << 2) | wid;           // 0..2047
  for (int t = gw; t < NTOK; t += 2048) {
    const float* xt = x + (size_t)t * 128;
    const float vx0 = xt[lane];
    const float vx1 = xt[64 + lane];
    float accq = bq, acck = bk, accv = bv, acco = bo;
    #pragma unroll 2
    for (int dp4 = 0; dp4 < 16; ++dp4) {
      const float xsrc = (dp4 < 8) ? vx0 : vx1;     // uniform select
      const int   db   = (dp4 * 8) & 63;            // base d within xsrc
      const int   off  = (dp4 * 4) ^ ((lane & 7) << 2);
      const uint4 uq = *(const uint4*)&wlds[0][lane][off];
      const uint4 uk = *(const uint4*)&wlds[1][lane][off];
      const uint4 uv = *(const uint4*)&wlds[2][lane][off];
      const uint4 uo = *(const uint4*)&wlds[3][lane][off];
      #pragma unroll
      for (int e = 0; e < 4; ++e) {
        const int d0 = db + 2 * e;
        const float xa = readlane_f(xsrc, d0);
        const float xb = readlane_f(xsrc, d0 + 1);
        const uint32_t cq = (&uq.x)[e];
        const uint32_t ck = (&uk.x)[e];
        const uint32_t cv = (&uv.x)[e];
        const uint32_t co = (&uo.x)[e];
        accq = fmaf(__uint_as_float(cq << 16), xa, accq);
        accq = fmaf(__uint_as_float(cq & 0xFFFF0000u), xb, accq);
        acck = fmaf(__uint_as_float(ck << 16), xa, acck);
        acck = fmaf(__uint_as_float(ck & 0xFFFF0000u), xb, acck);
        accv = fmaf(__uint_as_float(cv << 16), xa, accv);
        accv = fmaf(__uint_as_float(cv & 0xFFFF0000u), xb, accv);
        acco = fmaf(__uint_as_float(co << 16), xa, acco);
        acco = fmaf(__uint_as_float(co & 0xFFFF0000u), xb, acco);
      }
    }
    // gates in full f32
    float pi = fmaf(vx0, wi0, vx1 * wi1);
    float pf = fmaf(vx0, wf0, vx1 * wf1);
    pi = wave_sum64(pi);
    pf = wave_sum64(pf);
    const float it_ = __expf(pi + sbi);
    const float ft_ = 1.0f / (1.0f + __expf(-(pf + sbf)));

    float* Pt = P + (size_t)t * PPITCH;
    Pt[lane]        = accq;
    Pt[64 + lane]   = acck * 0.125f;                // 1/sqrt(64), after bias
    Pt[128 + lane]  = accv;
    Pt[192 + lane]  = 1.0f / (1.0f + __expf(-acco)); // o_t = sigmoid
    if (lane == 0) { Pt[256] = it_; Pt[257] = ft_; }
  }
}

// ---------------------------------------------------------------------------
// K2: expansion. One wave per token; lane = feature.
// h~ = (f*(c_prev@q) + i*v*(k.q)) / max(|n.q|,1)  (no need to re-read c_t)
// c_t[t][r][lane] = f*c_prev[r][lane] + (i*v[r])*k[lane]   -- 64 coalesced rows
// ---------------------------------------------------------------------------
__global__ void __launch_bounds__(256)
expand_kernel(const float* __restrict__ P,
              const float* __restrict__ c_prev,
              const float* __restrict__ n_prev,
              float* __restrict__ h_out,
              float* __restrict__ c_out,
              float* __restrict__ n_out)
{
  __shared__ float cp[64][65];   // +1 pad: conflict-free row AND column access
  const int tid = threadIdx.x;
  for (int idx = tid; idx < 4096; idx += 256)
    cp[idx >> 6][idx & 63] = c_prev[idx];
  __syncthreads();

  const int lane = tid & 63;
  const int wid  = tid >> 6;
  const float npv = n_prev[lane];
  const int gw = (blockIdx.x << 2) | wid;           // 0..4095
  for (int t = gw; t < NTOK; t += 4096) {
    const float* Pt = P + (size_t)t * PPITCH;
    const float q   = Pt[lane];
    const float k   = Pt[64 + lane];
    const float v   = Pt[128 + lane];
    const float o   = Pt[192 + lane];
    const float it_ = Pt[256];                       // broadcast
    const float ft_ = Pt[257];

    const float n_val = fmaf(ft_, npv, it_ * k);
    n_out[(size_t)t * 64 + lane] = n_val;

    const float nq = wave_sum64(n_val * q);
    const float kq = wave_sum64(k * q);

    // cpq[lane] = sum_j c_prev[lane][j] * q[j]
    float c0 = 0.f, c1 = 0.f, c2 = 0.f, c3 = 0.f;
    #pragma unroll 4
    for (int j = 0; j < 64; j += 4) {
      c0 = fmaf(cp[lane][j],     readlane_f(q, j),     c0);
      c1 = fmaf(cp[lane][j + 1], readlane_f(q, j + 1), c1);
      c2 = fmaf(cp[lane][j + 2], readlane_f(q, j + 2), c2);
      c3 = fmaf(cp[lane][j + 3], readlane_f(q, j + 3), c3);
    }
    const float cpq = (c0 + c1) + (c2 + c3);

    const float inv  = 1.0f / fmaxf(fabsf(nq), 1.0f);
    const float htil = fmaf(ft_, cpq, it_ * v * kq) * inv;
    h_out[(size_t)t * 64 + lane] = o * htil;

    const float iv = it_ * v;
    float* ct = c_out + (size_t)t * 4096;
    #pragma unroll 8
    for (int r = 0; r < 64; ++r) {
      ct[r * 64 + lane] = fmaf(ft_, cp[r][lane], readlane_f(iv, r) * k);
    }
  }
}

extern "C" void kernel_launch(void* const* d_in, const int* in_sizes, int n_in,
                              void* d_out, int out_size, void* d_ws, size_t ws_size,
                              hipStream_t stream) {
  const float* x      = (const float*)d_in[0];
  const float* c_prev = (const float*)d_in[1];
  const float* n_prev = (const float*)d_in[2];
  const float* w_q = (const float*)d_in[3];
  const float* b_q = (const float*)d_in[4];
  const float* w_k = (const float*)d_in[5];
  const float* b_k = (const float*)d_in[6];
  const float* w_v = (const float*)d_in[7];
  const float* b_v = (const float*)d_in[8];
  const float* w_i = (const float*)d_in[9];
  const float* b_i = (const float*)d_in[10];
  const float* w_f = (const float*)d_in[11];
  const float* b_f = (const float*)d_in[12];
  const float* w_o = (const float*)d_in[13];
  const float* b_o = (const float*)d_in[14];

  float* P = (float*)d_ws;                    // 16384 * 264 * 4 = 17.3 MB
  float* h_out = (float*)d_out;               // 8*2048*64      = 1,048,576
  float* c_out = h_out + 1048576;             // 8*2048*64*64   = 67,108,864
  float* n_out = c_out + 67108864;            // 8*2048*64      = 1,048,576

  proj_kernel<<<512, 256, 0, stream>>>(x, w_q, b_q, w_k, b_k, w_v, b_v,
                                       w_i, b_i, w_f, b_f, w_o, b_o, P);
  expand_kernel<<<1024, 256, 0, stream>>>(P, c_prev, n_prev, h_out, c_out, n_out);
}

// Round 2
// 86.671 us; speedup vs baseline: 1.1272x; 1.1272x over previous
//
#include <hip/hip_runtime.h>
#include <cstdint>

#define NTOK 16384
#define PPITCH 264

typedef float f4 __attribute__((ext_vector_type(4)));

__device__ __forceinline__ float readlane_f(float v, int lane) {
  return __int_as_float(__builtin_amdgcn_readlane(__float_as_int(v), lane));
}

__device__ __forceinline__ float wave_sum64(float v) {
  #pragma unroll
  for (int s = 1; s < 64; s <<= 1) v += __shfl_xor(v, s, 64);
  return v;
}

__device__ __forceinline__ float half_sum32(float v) {
  // sum within each 32-lane half (lanes 0-31 and 32-63 independently)
  #pragma unroll
  for (int s = 1; s < 32; s <<= 1) v += __shfl_xor(v, s, 64);
  return v;
}

__device__ __forceinline__ float elemf(f4 v, int e) {
  return e == 0 ? v.x : e == 1 ? v.y : e == 2 ? v.z : v.w;
}

// ---------------------------------------------------------------------------
// K1: projections. One wave per 8-token group; lane = output feature.
// Weights staged once per block in LDS as packed bf16 pairs (XOR-swizzled).
// Each weight fragment is read ONCE and applied to 8 tokens (8x less LDS
// traffic than round 1, which was LDS-pipe bound).
// x for the 8 tokens (1024 floats) is held as 4 float4 chunks per lane and
// broadcast via v_readlane (indices wave-uniform).
// ---------------------------------------------------------------------------
__global__ void __launch_bounds__(256, 2)
proj_kernel(const float* __restrict__ x,
            const float* __restrict__ w_q, const float* __restrict__ b_q,
            const float* __restrict__ w_k, const float* __restrict__ b_k,
            const float* __restrict__ w_v, const float* __restrict__ b_v,
            const float* __restrict__ w_i, const float* __restrict__ b_i,
            const float* __restrict__ w_f, const float* __restrict__ b_f,
            const float* __restrict__ w_o, const float* __restrict__ b_o,
            float* __restrict__ P)
{
  __shared__ uint32_t wlds[4][64][64];   // 64 KB
  const int tid = threadIdx.x;
  {
    const float* Ws[4] = {w_q, w_k, w_v, w_o};
    #pragma unroll
    for (int m = 0; m < 4; ++m) {
      const float* W = Ws[m];
      #pragma unroll
      for (int it = 0; it < 16; ++it) {
        int idx = it * 256 + tid;      // 0..4095
        int dp  = idx >> 6;            // d-pair 0..63
        int j   = idx & 63;            // output column
        uint32_t ua = __float_as_uint(W[(2 * dp)     * 64 + j]);
        uint32_t ub = __float_as_uint(W[(2 * dp + 1) * 64 + j]);
        ua = (ua + 0x7FFFu + ((ua >> 16) & 1u)) >> 16;   // rne bf16
        ub = (ub + 0x7FFFu + ((ub >> 16) & 1u)) >> 16;
        wlds[m][j][dp ^ ((j & 7) << 2)] = (ua & 0xFFFFu) | (ub << 16);
      }
    }
  }
  __syncthreads();

  const int lane = tid & 63;
  const int wid  = tid >> 6;
  const int t0   = (((blockIdx.x << 2) | wid) << 3);   // 8 tokens per wave

  // x chunks: flat[0..1023] = x[t0..t0+7][0..127]; chunk c = flat[256c..]
  // x[t][d] lives in chunk (tt>>1), lane ((tt&1)<<5)+(d>>2), elem (d&3)
  const f4* xp = (const f4*)(x + (size_t)t0 * 128);
  f4 xc[4];
  xc[0] = xp[lane];
  xc[1] = xp[64 + lane];
  xc[2] = xp[128 + lane];
  xc[3] = xp[192 + lane];

  const float bq = b_q[lane], bk = b_k[lane], bv = b_v[lane], bo = b_o[lane];
  float accq[8], acck[8], accv[8], acco[8];
  #pragma unroll
  for (int tt = 0; tt < 8; ++tt) { accq[tt] = bq; acck[tt] = bk; accv[tt] = bv; acco[tt] = bo; }

  #pragma unroll 2
  for (int dp4 = 0; dp4 < 16; ++dp4) {
    const int off = (dp4 * 4) ^ ((lane & 7) << 2);
    const uint4 uq = *(const uint4*)&wlds[0][lane][off];
    const uint4 uk = *(const uint4*)&wlds[1][lane][off];
    const uint4 uv = *(const uint4*)&wlds[2][lane][off];
    const uint4 uo = *(const uint4*)&wlds[3][lane][off];
    #pragma unroll
    for (int e = 0; e < 4; ++e) {
      const int d0 = dp4 * 8 + 2 * e;                // uniform (runtime ok for readlane)
      const uint32_t cq = (&uq.x)[e], ck = (&uk.x)[e];
      const uint32_t cv = (&uv.x)[e], co = (&uo.x)[e];
      const float wq0 = __uint_as_float(cq << 16), wq1 = __uint_as_float(cq & 0xFFFF0000u);
      const float wk0 = __uint_as_float(ck << 16), wk1 = __uint_as_float(ck & 0xFFFF0000u);
      const float wv0 = __uint_as_float(cv << 16), wv1 = __uint_as_float(cv & 0xFFFF0000u);
      const float wo0 = __uint_as_float(co << 16), wo1 = __uint_as_float(co & 0xFFFF0000u);
      const int lsub = d0 >> 2;                      // (d0>>2) == (d1>>2)
      #pragma unroll
      for (int tt = 0; tt < 8; ++tt) {
        const int lidx = ((tt & 1) << 5) + lsub;
        const float xa = readlane_f(elemf(xc[tt >> 1], (2 * e) & 3), lidx);
        const float xb = readlane_f(elemf(xc[tt >> 1], (2 * e + 1) & 3), lidx);
        accq[tt] = fmaf(wq0, xa, accq[tt]); accq[tt] = fmaf(wq1, xb, accq[tt]);
        acck[tt] = fmaf(wk0, xa, acck[tt]); acck[tt] = fmaf(wk1, xb, acck[tt]);
        accv[tt] = fmaf(wv0, xa, accv[tt]); accv[tt] = fmaf(wv1, xb, accv[tt]);
        acco[tt] = fmaf(wo0, xa, acco[tt]); acco[tt] = fmaf(wo1, xb, acco[tt]);
      }
    }
  }

  // gates in full f32 using the chunk distribution:
  // lane l holds x[2c+(l>>5)][4*(l&31)+e] in xc[c].e
  const int dbase = (lane & 31) << 2;
  const f4 wi4 = *(const f4*)&w_i[dbase];
  const f4 wf4 = *(const f4*)&w_f[dbase];
  const float sbi = b_i[0], sbf = b_f[0];
  #pragma unroll
  for (int c = 0; c < 4; ++c) {
    float pi = xc[c].x * wi4.x + xc[c].y * wi4.y + xc[c].z * wi4.z + xc[c].w * wi4.w;
    float pf = xc[c].x * wf4.x + xc[c].y * wf4.y + xc[c].z * wf4.z + xc[c].w * wf4.w;
    pi = half_sum32(pi);
    pf = half_sum32(pf);
    if ((lane & 31) == 0) {
      const int t = t0 + 2 * c + (lane >> 5);
      P[(size_t)t * PPITCH + 256] = __expf(pi + sbi);
      P[(size_t)t * PPITCH + 257] = 1.0f / (1.0f + __expf(-(pf + sbf)));
    }
  }

  #pragma unroll
  for (int tt = 0; tt < 8; ++tt) {
    float* Pt = P + (size_t)(t0 + tt) * PPITCH;
    Pt[lane]       = accq[tt];
    Pt[64 + lane]  = acck[tt] * 0.125f;                  // 1/sqrt(64)
    Pt[128 + lane] = accv[tt];
    Pt[192 + lane] = 1.0f / (1.0f + __expf(-acco[tt]));  // o_t
  }
}

// ---------------------------------------------------------------------------
// K2: expansion, float4-vectorized. One wave per token.
// h~ = (f*(c_prev@q) + i*v*(k.q)) / max(|n.q|,1)   (c_t is write-only)
// c stores: 16 dwordx4 per token, lane l -> row 4s+(l>>4), cols 4(l&15)..+3
// (address = base + 256s + 4l floats: perfectly contiguous 1KB per instr),
// nontemporal (268 MB streamed, never re-read).
// ---------------------------------------------------------------------------
__global__ void __launch_bounds__(256)
expand_kernel(const float* __restrict__ P,
              const float* __restrict__ c_prev,
              const float* __restrict__ n_prev,
              float* __restrict__ h_out,
              float* __restrict__ c_out,
              float* __restrict__ n_out)
{
  __shared__ float cp[64][68];   // stride 68 floats = 17 16B-units (odd): spread banks
  const int tid = threadIdx.x;
  for (int idx = tid; idx < 4096; idx += 256)
    cp[idx >> 6][idx & 63] = c_prev[idx];
  __syncthreads();

  const int lane = tid & 63;
  const int wid  = tid >> 6;
  const float npv = n_prev[lane];
  const int gw = (blockIdx.x << 2) | wid;              // 0..4095
  const int m  = lane & 15;

  for (int t = gw; t < NTOK; t += 4096) {
    const float* Pt = P + (size_t)t * PPITCH;
    const float q   = Pt[lane];
    const float k   = Pt[64 + lane];
    const float v   = Pt[128 + lane];
    const float o   = Pt[192 + lane];
    const float it_ = Pt[256];
    const float ft_ = Pt[257];

    const float n_val = fmaf(ft_, npv, it_ * k);
    n_out[(size_t)t * 64 + lane] = n_val;

    const float nq = wave_sum64(n_val * q);
    const float kq = wave_sum64(k * q);

    // cpq[lane] = sum_j c_prev[lane][j] * q[j], float4 LDS reads
    float c0 = 0.f, c1 = 0.f, c2 = 0.f, c3 = 0.f;
    #pragma unroll
    for (int j = 0; j < 16; ++j) {
      const f4 r4 = *(const f4*)&cp[lane][4 * j];
      c0 = fmaf(r4.x, readlane_f(q, 4 * j),     c0);
      c1 = fmaf(r4.y, readlane_f(q, 4 * j + 1), c1);
      c2 = fmaf(r4.z, readlane_f(q, 4 * j + 2), c2);
      c3 = fmaf(r4.w, readlane_f(q, 4 * j + 3), c3);
    }
    const float cpq = (c0 + c1) + (c2 + c3);

    const float inv  = 1.0f / fmaxf(fabsf(nq), 1.0f);
    const float htil = fmaf(ft_, cpq, it_ * v * kq) * inv;
    h_out[(size_t)t * 64 + lane] = o * htil;

    // c_t stores
    const float iv = it_ * v;
    const float k40 = __shfl(k, 4 * m, 64);
    const float k41 = __shfl(k, 4 * m + 1, 64);
    const float k42 = __shfl(k, 4 * m + 2, 64);
    const float k43 = __shfl(k, 4 * m + 3, 64);
    f4* ct = (f4*)(c_out + (size_t)t * 4096);
    #pragma unroll
    for (int s = 0; s < 16; ++s) {
      const int row = 4 * s + (lane >> 4);
      const float ivr = __shfl(iv, row, 64);
      const f4 c4 = *(const f4*)&cp[row][4 * m];
      f4 val;
      val.x = fmaf(ft_, c4.x, ivr * k40);
      val.y = fmaf(ft_, c4.y, ivr * k41);
      val.z = fmaf(ft_, c4.z, ivr * k42);
      val.w = fmaf(ft_, c4.w, ivr * k43);
      __builtin_nontemporal_store(val, ct + (s * 64 + lane));
    }
  }
}

extern "C" void kernel_launch(void* const* d_in, const int* in_sizes, int n_in,
                              void* d_out, int out_size, void* d_ws, size_t ws_size,
                              hipStream_t stream) {
  const float* x      = (const float*)d_in[0];
  const float* c_prev = (const float*)d_in[1];
  const float* n_prev = (const float*)d_in[2];
  const float* w_q = (const float*)d_in[3];
  const float* b_q = (const float*)d_in[4];
  const float* w_k = (const float*)d_in[5];
  const float* b_k = (const float*)d_in[6];
  const float* w_v = (const float*)d_in[7];
  const float* b_v = (const float*)d_in[8];
  const float* w_i = (const float*)d_in[9];
  const float* b_i = (const float*)d_in[10];
  const float* w_f = (const float*)d_in[11];
  const float* b_f = (const float*)d_in[12];
  const float* w_o = (const float*)d_in[13];
  const float* b_o = (const float*)d_in[14];

  float* P = (float*)d_ws;                    // 16384 * 264 * 4 = 17.3 MB
  float* h_out = (float*)d_out;               // 1,048,576
  float* c_out = h_out + 1048576;             // 67,108,864
  float* n_out = c_out + 67108864;            // 1,048,576

  proj_kernel<<<512, 256, 0, stream>>>(x, w_q, b_q, w_k, b_k, w_v, b_v,
                                       w_i, b_i, w_f, b_f, w_o, b_o, P);
  expand_kernel<<<1024, 256, 0, stream>>>(P, c_prev, n_prev, h_out, c_out, n_out);
}

// Round 3
// 60.502 us; speedup vs baseline: 1.6148x; 1.4325x over previous
//
#include <hip/hip_runtime.h>
#include <cstdint>

#define NTOK 16384

typedef float f4 __attribute__((ext_vector_type(4)));

__device__ __forceinline__ float readlane_f(float v, int lane) {
  return __int_as_float(__builtin_amdgcn_readlane(__float_as_int(v), lane));
}

__device__ __forceinline__ float wave_sum64(float v) {
  #pragma unroll
  for (int s = 1; s < 64; s <<= 1) v += __shfl_xor(v, s, 64);
  return v;
}

__device__ __forceinline__ float half_sum32(float v) {
  // independent sums within lanes 0-31 and 32-63
  #pragma unroll
  for (int s = 1; s < 32; s <<= 1) v += __shfl_xor(v, s, 64);
  return v;
}

__device__ __forceinline__ float elemf(f4 v, int e) {
  return e == 0 ? v.x : e == 1 ? v.y : e == 2 ? v.z : v.w;
}

// ---------------------------------------------------------------------------
// Fully fused mLSTM: one 512-thread block per CU, 8 waves, 8 tokens per wave.
//  Phase A (registers): q/k/v/o projections (bf16 weights from LDS, one
//    fragment read amortized over 8 tokens) + i/f gates in full f32.
//  Phase B (per token, straight from registers):
//    n = f*n_prev + i*k                     -> n_out
//    h = o * (f*(c_prev@q) + i*v*(k.q)) / max(|n.q|,1)   -> h_out
//    c = f*c_prev + i*outer(v,k)            -> c_out (64 x dwordx4, coalesced)
//  No intermediate global buffer; c_t is write-only (h~ uses the algebraic
//  form, not the materialized matrix).
// ---------------------------------------------------------------------------
__global__ void __launch_bounds__(512, 2)
fused_kernel(const float* __restrict__ x,
             const float* __restrict__ c_prev,
             const float* __restrict__ n_prev,
             const float* __restrict__ w_q, const float* __restrict__ b_q,
             const float* __restrict__ w_k, const float* __restrict__ b_k,
             const float* __restrict__ w_v, const float* __restrict__ b_v,
             const float* __restrict__ w_i, const float* __restrict__ b_i,
             const float* __restrict__ w_f, const float* __restrict__ b_f,
             const float* __restrict__ w_o, const float* __restrict__ b_o,
             float* __restrict__ h_out,
             float* __restrict__ c_out,
             float* __restrict__ n_out)
{
  __shared__ uint32_t wlds[4][64][64];   // 64 KB: bf16-pair-packed weights
  __shared__ float    cp[64][68];        // 17 KB: c_prev, padded stride
  const int tid = threadIdx.x;

  {
    const float* Ws[4] = {w_q, w_k, w_v, w_o};
    #pragma unroll
    for (int m = 0; m < 4; ++m) {
      const float* W = Ws[m];
      #pragma unroll
      for (int it = 0; it < 8; ++it) {
        int idx = it * 512 + tid;      // 0..4095
        int dp  = idx >> 6;            // d-pair 0..63
        int j   = idx & 63;            // output column
        uint32_t ua = __float_as_uint(W[(2 * dp)     * 64 + j]);
        uint32_t ub = __float_as_uint(W[(2 * dp + 1) * 64 + j]);
        ua = (ua + 0x7FFFu + ((ua >> 16) & 1u)) >> 16;   // rne bf16
        ub = (ub + 0x7FFFu + ((ub >> 16) & 1u)) >> 16;
        wlds[m][j][dp ^ ((j & 7) << 2)] = (ua & 0xFFFFu) | (ub << 16);
      }
    }
  }
  for (int idx = tid; idx < 4096; idx += 512)
    cp[idx >> 6][idx & 63] = c_prev[idx];
  __syncthreads();

  const int lane = tid & 63;
  const int wid  = tid >> 6;
  const int t0   = blockIdx.x * 64 + wid * 8;    // 8 tokens per wave

  // ---- Phase A: projections for 8 tokens ----
  // flat[0..1023] = x[t0..t0+7][0..127]; x[t0+tt][d] -> chunk tt>>1,
  // lane ((tt&1)<<5)+(d>>2), elem d&3
  const f4* xp = (const f4*)(x + (size_t)t0 * 128);
  f4 xc[4];
  xc[0] = xp[lane];
  xc[1] = xp[64 + lane];
  xc[2] = xp[128 + lane];
  xc[3] = xp[192 + lane];

  const float bq = b_q[lane], bk = b_k[lane], bv = b_v[lane], bo = b_o[lane];
  float accq[8], acck[8], accv[8], acco[8];
  #pragma unroll
  for (int tt = 0; tt < 8; ++tt) { accq[tt] = bq; acck[tt] = bk; accv[tt] = bv; acco[tt] = bo; }

  #pragma unroll 2
  for (int dp4 = 0; dp4 < 16; ++dp4) {
    const int off = (dp4 * 4) ^ ((lane & 7) << 2);
    const uint4 uq = *(const uint4*)&wlds[0][lane][off];
    const uint4 uk = *(const uint4*)&wlds[1][lane][off];
    const uint4 uv = *(const uint4*)&wlds[2][lane][off];
    const uint4 uo = *(const uint4*)&wlds[3][lane][off];
    #pragma unroll
    for (int e = 0; e < 4; ++e) {
      const uint32_t cq = (&uq.x)[e], ck = (&uk.x)[e];
      const uint32_t cv = (&uv.x)[e], co = (&uo.x)[e];
      const float wq0 = __uint_as_float(cq << 16), wq1 = __uint_as_float(cq & 0xFFFF0000u);
      const float wk0 = __uint_as_float(ck << 16), wk1 = __uint_as_float(ck & 0xFFFF0000u);
      const float wv0 = __uint_as_float(cv << 16), wv1 = __uint_as_float(cv & 0xFFFF0000u);
      const float wo0 = __uint_as_float(co << 16), wo1 = __uint_as_float(co & 0xFFFF0000u);
      const int lsub = 2 * dp4 + (e >> 1);           // (dp4*8+2e)>>2, wave-uniform
      #pragma unroll
      for (int tt = 0; tt < 8; ++tt) {
        const int lidx = ((tt & 1) << 5) + lsub;
        const float xa = readlane_f(elemf(xc[tt >> 1], (2 * e) & 3), lidx);
        const float xb = readlane_f(elemf(xc[tt >> 1], (2 * e + 1) & 3), lidx);
        accq[tt] = fmaf(wq0, xa, accq[tt]); accq[tt] = fmaf(wq1, xb, accq[tt]);
        acck[tt] = fmaf(wk0, xa, acck[tt]); acck[tt] = fmaf(wk1, xb, acck[tt]);
        accv[tt] = fmaf(wv0, xa, accv[tt]); accv[tt] = fmaf(wv1, xb, accv[tt]);
        acco[tt] = fmaf(wo0, xa, acco[tt]); acco[tt] = fmaf(wo1, xb, acco[tt]);
      }
    }
  }

  // gates, full f32: lane l holds x[t0+2c+(l>>5)][4*(l&31)+e] in xc[c].e
  float itv[8], ftv[8];
  {
    const int dbase = (lane & 31) << 2;
    const f4 wi4 = *(const f4*)&w_i[dbase];
    const f4 wf4 = *(const f4*)&w_f[dbase];
    const float sbi = b_i[0], sbf = b_f[0];
    #pragma unroll
    for (int c = 0; c < 4; ++c) {
      float pi = xc[c].x * wi4.x + xc[c].y * wi4.y + xc[c].z * wi4.z + xc[c].w * wi4.w;
      float pf = xc[c].x * wf4.x + xc[c].y * wf4.y + xc[c].z * wf4.z + xc[c].w * wf4.w;
      pi = half_sum32(pi);
      pf = half_sum32(pf);
      itv[2 * c]     = __expf(readlane_f(pi, 0)  + sbi);
      itv[2 * c + 1] = __expf(readlane_f(pi, 32) + sbi);
      ftv[2 * c]     = 1.0f / (1.0f + __expf(-(readlane_f(pf, 0)  + sbf)));
      ftv[2 * c + 1] = 1.0f / (1.0f + __expf(-(readlane_f(pf, 32) + sbf)));
    }
  }

  // ---- Phase B: expansion per token, straight from registers ----
  const float npv = n_prev[lane];
  const int m = lane & 15;
  #pragma unroll
  for (int tt = 0; tt < 8; ++tt) {
    const size_t t = (size_t)(t0 + tt);
    const float q   = accq[tt];
    const float k   = acck[tt] * 0.125f;             // 1/sqrt(64)
    const float v   = accv[tt];
    const float o   = 1.0f / (1.0f + __expf(-acco[tt]));
    const float it_ = itv[tt];
    const float ft_ = ftv[tt];

    const float n_val = fmaf(ft_, npv, it_ * k);
    n_out[t * 64 + lane] = n_val;

    const float nq = wave_sum64(n_val * q);
    const float kq = wave_sum64(k * q);

    // cpq[lane] = sum_j c_prev[lane][j] * q[j]
    float c0 = 0.f, c1 = 0.f, c2 = 0.f, c3 = 0.f;
    #pragma unroll
    for (int j = 0; j < 16; ++j) {
      const f4 r4 = *(const f4*)&cp[lane][4 * j];
      c0 = fmaf(r4.x, readlane_f(q, 4 * j),     c0);
      c1 = fmaf(r4.y, readlane_f(q, 4 * j + 1), c1);
      c2 = fmaf(r4.z, readlane_f(q, 4 * j + 2), c2);
      c3 = fmaf(r4.w, readlane_f(q, 4 * j + 3), c3);
    }
    const float cpq = (c0 + c1) + (c2 + c3);

    const float inv  = 1.0f / fmaxf(fabsf(nq), 1.0f);
    const float htil = fmaf(ft_, cpq, it_ * v * kq) * inv;
    h_out[t * 64 + lane] = o * htil;

    // c_t: lane l -> row 4s+(l>>4), cols 4m..4m+3; 16 x 1KB contiguous stores
    const float iv = it_ * v;
    const float k40 = __shfl(k, 4 * m, 64);
    const float k41 = __shfl(k, 4 * m + 1, 64);
    const float k42 = __shfl(k, 4 * m + 2, 64);
    const float k43 = __shfl(k, 4 * m + 3, 64);
    f4* ct = (f4*)(c_out + t * 4096);
    #pragma unroll
    for (int s = 0; s < 16; ++s) {
      const int row = 4 * s + (lane >> 4);
      const float ivr = __shfl(iv, row, 64);
      const f4 c4 = *(const f4*)&cp[row][4 * m];
      f4 val;
      val.x = fmaf(ft_, c4.x, ivr * k40);
      val.y = fmaf(ft_, c4.y, ivr * k41);
      val.z = fmaf(ft_, c4.z, ivr * k42);
      val.w = fmaf(ft_, c4.w, ivr * k43);
      ct[s * 64 + lane] = val;
    }
  }
}

extern "C" void kernel_launch(void* const* d_in, const int* in_sizes, int n_in,
                              void* d_out, int out_size, void* d_ws, size_t ws_size,
                              hipStream_t stream) {
  const float* x      = (const float*)d_in[0];
  const float* c_prev = (const float*)d_in[1];
  const float* n_prev = (const float*)d_in[2];
  const float* w_q = (const float*)d_in[3];
  const float* b_q = (const float*)d_in[4];
  const float* w_k = (const float*)d_in[5];
  const float* b_k = (const float*)d_in[6];
  const float* w_v = (const float*)d_in[7];
  const float* b_v = (const float*)d_in[8];
  const float* w_i = (const float*)d_in[9];
  const float* b_i = (const float*)d_in[10];
  const float* w_f = (const float*)d_in[11];
  const float* b_f = (const float*)d_in[12];
  const float* w_o = (const float*)d_in[13];
  const float* b_o = (const float*)d_in[14];

  float* h_out = (float*)d_out;               // 1,048,576
  float* c_out = h_out + 1048576;             // 67,108,864
  float* n_out = c_out + 67108864;            // 1,048,576

  fused_kernel<<<256, 512, 0, stream>>>(x, c_prev, n_prev,
                                        w_q, b_q, w_k, b_k, w_v, b_v,
                                        w_i, b_i, w_f, b_f, w_o, b_o,
                                        h_out, c_out, n_out);
}